// Round 5
// baseline (135.501 us; speedup 1.0000x reference)
//
#include <hip/hip_runtime.h>
#include <hip/hip_bf16.h>

#define IN_C  32
#define CH    35
#define P_CNT 369
#define NPAIR 64
#define NALL  100000
#define NTILE 6250          // NALL / 16 exactly
#define TT    8             // feature tiles per wave

// param offsets within a proposal's 369 floats
#define OW1 0               // w1[c][h] = c*8 + h   (c < 35)
#define OB1 280
#define OW2 288             // w2[h][k] = 288 + h*8 + k
#define OB2 352
#define OW3 360
#define OB3 368

// d_ws byte offsets
#define WS_W1F 0            // ushort [64 pair][2 kh][64 lane][8]   131072 B
#define WS_W2F 131072       // ushort [64][64 lane][4]              32768 B
#define WS_B1F 163840       // float  [64][64 lane][4]              65536 B
#define WS_B2F 229376       // float  [64][64 lane][4]              65536 B
#define WS_W3F 294912       // float  [64][64 lane][4]              65536 B
#define WS_B3F 360448       // float  [64][2]                       512 B

typedef short  bf16x8 __attribute__((ext_vector_type(8)));
typedef short  bf16x4 __attribute__((ext_vector_type(4)));
typedef float  f32x4  __attribute__((ext_vector_type(4)));

static __device__ inline unsigned short f2bf(float x) {   // software RNE (prep + fallback)
    union { float f; unsigned u; } v; v.f = x;
    unsigned r = v.u + 0x7FFFu + ((v.u >> 16) & 1u);
    return (unsigned short)(r >> 16);
}

// API-sanctioned packed f32->bf16 RNE (compiler emits native cvt on gfx950).
// Returns u32 with bf16(lo) in bits [15:0], bf16(hi) in bits [31:16].
static __device__ inline unsigned pack2bf(float lo, float hi) {
    __hip_bfloat162 h2 = __float22bfloat162_rn(make_float2(lo, hi));
    union { __hip_bfloat162 h; unsigned u; } c; c.h = h2; return c.u;
}

// ---------------- Prep: params for one pair + lane-exact fragment packing ----
__global__ __launch_bounds__(256) void prep_kernel(
        const float* __restrict__ prop,   // (128, 32)
        const float* __restrict__ W,      // (32, 369)
        const float* __restrict__ b,      // (369,)
        char* __restrict__ ws) {
    const int pp  = blockIdx.x;           // pair index 0..63
    const int tid = threadIdx.x;
    __shared__ float P[2][P_CNT];

    for (int idx = tid; idx < 2 * P_CNT; idx += 256) {
        const int pl = (idx >= P_CNT) ? 1 : 0;
        const int j  = idx - pl * P_CNT;
        const float* pr = prop + (size_t)(2 * pp + pl) * IN_C;
        float acc = b[j];
        #pragma unroll
        for (int c = 0; c < IN_C; ++c)
            acc = fmaf(pr[c], W[(size_t)c * P_CNT + j], acc);
        P[pl][j] = acc;
    }
    __syncthreads();

    if (tid >= 64) return;
    const int lane = tid;
    const int g = lane >> 4;
    const int m = lane & 15;

    // W1F: A-frag of 16x16x32. A[m = h-packed][k = c]; lane: row=m, k=8g+j
    {
        unsigned short* w1f = (unsigned short*)(ws + WS_W1F);
        const int pl = m >> 3, h = m & 7;
        #pragma unroll
        for (int kh = 0; kh < 2; ++kh)
            #pragma unroll
            for (int j = 0; j < 8; ++j) {
                const int c = kh * 32 + g * 8 + j;
                const float v = (c < CH) ? P[pl][OW1 + c * 8 + h] : 0.f;
                w1f[((size_t)(pp * 2 + kh) * 64 + lane) * 8 + j] = f2bf(v);
            }
    }
    // W2F: A-frag of 16x16x16 (block-diag packed w2). row=m, k=4g+r
    {
        unsigned short* w2f = (unsigned short*)(ws + WS_W2F);
        const int plj = m >> 3, jj = m & 7;
        #pragma unroll
        for (int r = 0; r < 4; ++r) {
            const int colh = g * 4 + r;
            const int ph = colh >> 3, h = colh & 7;
            const float v = (ph == plj) ? P[plj][OW2 + h * 8 + jj] : 0.f;
            w2f[((size_t)pp * 64 + lane) * 4 + r] = f2bf(v);
        }
    }
    // B1F / B2F / W3F: per-lane C-init rows (row = 4g + r, h/j-packed)
    {
        float* b1f = (float*)(ws + WS_B1F);
        float* b2f = (float*)(ws + WS_B2F);
        float* w3f = (float*)(ws + WS_W3F);
        #pragma unroll
        for (int r = 0; r < 4; ++r) {
            const int row = g * 4 + r;
            b1f[((size_t)pp * 64 + lane) * 4 + r] = P[row >> 3][OB1 + (row & 7)];
            b2f[((size_t)pp * 64 + lane) * 4 + r] = P[row >> 3][OB2 + (row & 7)];
            w3f[((size_t)pp * 64 + lane) * 4 + r] = P[row >> 3][OW3 + (row & 7)];
        }
    }
    if (lane < 2) ((float*)(ws + WS_B3F))[pp * 2 + lane] = P[lane][OB3];
}

// ---------------- Main: one wave per 8-tile group (128 rows), 16 pairs -------
__global__ __launch_bounds__(256) void mlp_kernel(
        const float* __restrict__ allf,   // (100000, 35)
        const char* __restrict__ ws,
        float* __restrict__ out) {        // (128, 100000)
    const int lane = threadIdx.x & 63;
    const int wave = threadIdx.x >> 6;
    const int gidx = blockIdx.x * 4 + wave;   // tile-group index
    const int tbase = gidx * TT;
    if (tbase >= NTILE) return;
    const int g   = lane >> 4;
    const int col = lane & 15;

    // Feature B-fragments for TT tiles: B[k=c][n=a]; lane: col=a, k=8g+j
    bf16x8 bf0[TT], bf1[TT];
    #pragma unroll
    for (int tt = 0; tt < TT; ++tt) {
        const int tile = tbase + tt;
        float fv0[8], fv1[8];
        if (tile < NTILE) {
            const float* fr = allf + (size_t)(tile * 16 + col) * CH;
            #pragma unroll
            for (int j = 0; j < 8; ++j) {
                fv0[j] = fr[g * 8 + j];                     // c = 0..31
                const int c1 = 32 + g * 8 + j;
                fv1[j] = (c1 < CH) ? fr[c1] : 0.f;
            }
        } else {
            #pragma unroll
            for (int j = 0; j < 8; ++j) { fv0[j] = 0.f; fv1[j] = 0.f; }
        }
        union { unsigned u[4]; bf16x8 v; } a0, a1;
        #pragma unroll
        for (int q = 0; q < 4; ++q) {
            a0.u[q] = pack2bf(fv0[2 * q], fv0[2 * q + 1]);
            a1.u[q] = pack2bf(fv1[2 * q], fv1[2 * q + 1]);
        }
        bf0[tt] = a0.v; bf1[tt] = a1.v;
    }

    const bf16x8* __restrict__ w1f = (const bf16x8*)(ws + WS_W1F);
    const bf16x4* __restrict__ w2f = (const bf16x4*)(ws + WS_W2F);
    const f32x4*  __restrict__ b1f = (const f32x4*)(ws + WS_B1F);
    const f32x4*  __restrict__ b2f = (const f32x4*)(ws + WS_B2F);
    const f32x4*  __restrict__ w3f = (const f32x4*)(ws + WS_W3F);
    const float2* __restrict__ b3f = (const float2*)(ws + WS_B3F);

    const int ppbase = blockIdx.y * 16;
    #pragma unroll 1
    for (int i = 0; i < 16; ++i) {
        const int pp = ppbase + i;
        const bf16x8 w1a = w1f[(pp * 2 + 0) * 64 + lane];
        const bf16x8 w1b = w1f[(pp * 2 + 1) * 64 + lane];
        const bf16x4 w2v = w2f[pp * 64 + lane];
        const f32x4  b1v = b1f[pp * 64 + lane];
        const f32x4  b2v = b2f[pp * 64 + lane];
        const f32x4  w3v = w3f[pp * 64 + lane];
        const float2 b3v = b3f[pp];

        const size_t pbase_out = (size_t)pp * 2 * NALL + (size_t)tbase * 16 + col;

        #pragma unroll
        for (int tt = 0; tt < TT; ++tt) {
            // ---- layer 1: C1[h-packed row, a]; rows 4g+r in lane
            f32x4 c1 = b1v;
            c1 = __builtin_amdgcn_mfma_f32_16x16x32_bf16(w1a, bf0[tt], c1, 0, 0, 0);
            c1 = __builtin_amdgcn_mfma_f32_16x16x32_bf16(w1b, bf1[tt], c1, 0, 0, 0);

            f32x4 c2;
#if __has_builtin(__builtin_amdgcn_mfma_f32_16x16x16bf16_1k)
            // ---- layer 2: C1 output layout == 16x16x16 B-fragment layout
            union { unsigned u[2]; bf16x4 v; } pb;
            pb.u[0] = pack2bf(fmaxf(c1[0], 0.f), fmaxf(c1[1], 0.f));
            pb.u[1] = pack2bf(fmaxf(c1[2], 0.f), fmaxf(c1[3], 0.f));
            c2 = __builtin_amdgcn_mfma_f32_16x16x16bf16_1k(w2v, pb.v, b2v, 0, 0, 0);
#else
            // ---- fallback: redistribute rows 4g+r -> k=8g+j via shfl, x32 MFMA
            float rl[4];
            #pragma unroll
            for (int r = 0; r < 4; ++r) rl[r] = fmaxf(c1[r], 0.f);
            bf16x8 pb8;
            #pragma unroll
            for (int j = 0; j < 8; ++j) {
                const int src = ((2 * g + (j >> 2)) << 4) + col;
                pb8[j] = (short)f2bf(__shfl(rl[j & 3], src, 64));
            }
            bf16x8 w28;
            #pragma unroll
            for (int r = 0; r < 4; ++r) { w28[r] = w2v[r]; w28[r + 4] = 0; }
            c2 = __builtin_amdgcn_mfma_f32_16x16x32_bf16(w28, pb8, b2v, 0, 0, 0);
#endif
            // ---- layer 3: 4-row partial dot + partner combine (xor 16)
            float s;
            s = fmaf(fmaxf(c2[0], 0.f), w3v[0], 0.f);
            s = fmaf(fmaxf(c2[1], 0.f), w3v[1], s);
            s = fmaf(fmaxf(c2[2], 0.f), w3v[2], s);
            s = fmaf(fmaxf(c2[3], 0.f), w3v[3], s);
            const float t = s + __shfl_xor(s, 16, 64);
            if (!(g & 1) && (tbase + tt) < NTILE) {
                const int pl = lane >> 5;               // 0: p even, 1: p odd
                out[pbase_out + (size_t)pl * NALL + tt * 16] =
                    t + (pl ? b3v.y : b3v.x);
            }
        }
    }
}

extern "C" void kernel_launch(void* const* d_in, const int* in_sizes, int n_in,
                              void* d_out, int out_size, void* d_ws, size_t ws_size,
                              hipStream_t stream) {
    const float* prop = (const float*)d_in[0];   // (128, 32)
    const float* allf = (const float*)d_in[1];   // (100000, 35)
    const float* W    = (const float*)d_in[2];   // (32, 369)
    const float* b    = (const float*)d_in[3];   // (369,)
    float* out = (float*)d_out;                  // (128, 100000, 1)
    char*  ws  = (char*)d_ws;

    prep_kernel<<<NPAIR, 256, 0, stream>>>(prop, W, b, ws);

    // 782 tile-groups (TT=8) packed 4 waves/block x 4 pair-quarters
    dim3 grid(196, 4);
    mlp_kernel<<<grid, 256, 0, stream>>>(allf, ws, out);
}

// Round 6
// 128.314 us; speedup vs baseline: 1.0560x; 1.0560x over previous
//
#include <hip/hip_runtime.h>
#include <hip/hip_bf16.h>

#define IN_C  32
#define CH    35
#define P_CNT 369
#define NPAIR 64
#define NALL  100000
#define NTILE 6250          // NALL / 16 exactly
#define TT    8             // feature tiles per wave
#define PP    8             // pairs per wave (grid.y = 64/PP)

// param offsets within a proposal's 369 floats
#define OW1 0               // w1[c][h] = c*8 + h   (c < 35)
#define OB1 280
#define OW2 288             // w2[h][k] = 288 + h*8 + k
#define OB2 352
#define OW3 360
#define OB3 368

// d_ws byte offsets
#define WS_W1F 0            // ushort [64 pair][2 kh][64 lane][8]   131072 B
#define WS_W2F 131072       // ushort [64][64 lane][4]              32768 B
#define WS_B1F 163840       // float  [64][64 lane][4]              65536 B
#define WS_B2F 229376       // float  [64][64 lane][4]              65536 B
#define WS_W3F 294912       // float  [64][64 lane][4]              65536 B
#define WS_B3F 360448       // float  [64][2]                       512 B

typedef short  bf16x8 __attribute__((ext_vector_type(8)));
typedef short  bf16x4 __attribute__((ext_vector_type(4)));
typedef float  f32x4  __attribute__((ext_vector_type(4)));

static __device__ inline unsigned short f2bf(float x) {   // software RNE (prep + fallback)
    union { float f; unsigned u; } v; v.f = x;
    unsigned r = v.u + 0x7FFFu + ((v.u >> 16) & 1u);
    return (unsigned short)(r >> 16);
}

// API-sanctioned packed f32->bf16 RNE (native cvt on gfx950).
static __device__ inline unsigned pack2bf(float lo, float hi) {
    __hip_bfloat162 h2 = __float22bfloat162_rn(make_float2(lo, hi));
    union { __hip_bfloat162 h; unsigned u; } c; c.h = h2; return c.u;
}

// ---------------- Prep: params for one pair + lane-exact fragment packing ----
__global__ __launch_bounds__(256) void prep_kernel(
        const float* __restrict__ prop,   // (128, 32)
        const float* __restrict__ W,      // (32, 369)
        const float* __restrict__ b,      // (369,)
        char* __restrict__ ws) {
    const int pp  = blockIdx.x;           // pair index 0..63
    const int tid = threadIdx.x;
    __shared__ float P[2][P_CNT];

    for (int idx = tid; idx < 2 * P_CNT; idx += 256) {
        const int pl = (idx >= P_CNT) ? 1 : 0;
        const int j  = idx - pl * P_CNT;
        const float* pr = prop + (size_t)(2 * pp + pl) * IN_C;
        float acc = b[j];
        #pragma unroll
        for (int c = 0; c < IN_C; ++c)
            acc = fmaf(pr[c], W[(size_t)c * P_CNT + j], acc);
        P[pl][j] = acc;
    }
    __syncthreads();

    if (tid >= 64) return;
    const int lane = tid;
    const int g = lane >> 4;
    const int m = lane & 15;

    // W1F: A-frag of 16x16x32. A[m = h-packed][k = c]; lane: row=m, k=8g+j
    {
        unsigned short* w1f = (unsigned short*)(ws + WS_W1F);
        const int pl = m >> 3, h = m & 7;
        #pragma unroll
        for (int kh = 0; kh < 2; ++kh)
            #pragma unroll
            for (int j = 0; j < 8; ++j) {
                const int c = kh * 32 + g * 8 + j;
                const float v = (c < CH) ? P[pl][OW1 + c * 8 + h] : 0.f;
                w1f[((size_t)(pp * 2 + kh) * 64 + lane) * 8 + j] = f2bf(v);
            }
    }
    // W2F: A-frag of 16x16x16 (block-diag packed w2). row=m, k=4g+r
    {
        unsigned short* w2f = (unsigned short*)(ws + WS_W2F);
        const int plj = m >> 3, jj = m & 7;
        #pragma unroll
        for (int r = 0; r < 4; ++r) {
            const int colh = g * 4 + r;
            const int ph = colh >> 3, h = colh & 7;
            const float v = (ph == plj) ? P[plj][OW2 + h * 8 + jj] : 0.f;
            w2f[((size_t)pp * 64 + lane) * 4 + r] = f2bf(v);
        }
    }
    // B1F / B2F / W3F: per-lane C-init rows (row = 4g + r, h/j-packed)
    {
        float* b1f = (float*)(ws + WS_B1F);
        float* b2f = (float*)(ws + WS_B2F);
        float* w3f = (float*)(ws + WS_W3F);
        #pragma unroll
        for (int r = 0; r < 4; ++r) {
            const int row = g * 4 + r;
            b1f[((size_t)pp * 64 + lane) * 4 + r] = P[row >> 3][OB1 + (row & 7)];
            b2f[((size_t)pp * 64 + lane) * 4 + r] = P[row >> 3][OB2 + (row & 7)];
            w3f[((size_t)pp * 64 + lane) * 4 + r] = P[row >> 3][OW3 + (row & 7)];
        }
    }
    if (lane < 2) ((float*)(ws + WS_B3F))[pp * 2 + lane] = P[lane][OB3];
}

// ---------------- Main: one wave per 8-tile group (128 rows), PP pairs -------
// __launch_bounds__(256, 2): VGPR cap ~128 so the TT=8 fragment array (64 VGPR)
// + per-pair weights (~32) stay register-resident (R5's 56-VGPR build was
// rematerializing fragment loads every pair iteration).
__global__ __launch_bounds__(256, 2) void mlp_kernel(
        const float* __restrict__ allf,   // (100000, 35)
        const char* __restrict__ ws,
        float* __restrict__ out) {        // (128, 100000)
    const int lane = threadIdx.x & 63;
    const int wave = threadIdx.x >> 6;
    const int gidx = blockIdx.x * 4 + wave;   // tile-group index
    const int tbase = gidx * TT;
    if (tbase >= NTILE) return;
    const int g   = lane >> 4;
    const int col = lane & 15;

    // Feature B-fragments for TT tiles: B[k=c][n=a]; lane: col=a, k=8g+j
    bf16x8 bf0[TT], bf1[TT];
    #pragma unroll
    for (int tt = 0; tt < TT; ++tt) {
        const int tile = tbase + tt;
        float fv0[8], fv1[8];
        if (tile < NTILE) {
            const float* fr = allf + (size_t)(tile * 16 + col) * CH;
            #pragma unroll
            for (int j = 0; j < 8; ++j) {
                fv0[j] = fr[g * 8 + j];                     // c = 0..31
                const int c1 = 32 + g * 8 + j;
                fv1[j] = (c1 < CH) ? fr[c1] : 0.f;
            }
        } else {
            #pragma unroll
            for (int j = 0; j < 8; ++j) { fv0[j] = 0.f; fv1[j] = 0.f; }
        }
        union { unsigned u[4]; bf16x8 v; } a0, a1;
        #pragma unroll
        for (int q = 0; q < 4; ++q) {
            a0.u[q] = pack2bf(fv0[2 * q], fv0[2 * q + 1]);
            a1.u[q] = pack2bf(fv1[2 * q], fv1[2 * q + 1]);
        }
        bf0[tt] = a0.v; bf1[tt] = a1.v;
    }

    const bf16x8* __restrict__ w1f = (const bf16x8*)(ws + WS_W1F);
    const bf16x4* __restrict__ w2f = (const bf16x4*)(ws + WS_W2F);
    const f32x4*  __restrict__ b1f = (const f32x4*)(ws + WS_B1F);
    const f32x4*  __restrict__ b2f = (const f32x4*)(ws + WS_B2F);
    const f32x4*  __restrict__ w3f = (const f32x4*)(ws + WS_W3F);
    const float2* __restrict__ b3f = (const float2*)(ws + WS_B3F);

    const int ppbase = blockIdx.y * PP;
    #pragma unroll 1
    for (int i = 0; i < PP; ++i) {
        const int pp = ppbase + i;
        const bf16x8 w1a = w1f[(pp * 2 + 0) * 64 + lane];
        const bf16x8 w1b = w1f[(pp * 2 + 1) * 64 + lane];
        const bf16x4 w2v = w2f[pp * 64 + lane];
        const f32x4  b1v = b1f[pp * 64 + lane];
        const f32x4  b2v = b2f[pp * 64 + lane];
        const f32x4  w3v = w3f[pp * 64 + lane];
        const float2 b3v = b3f[pp];

        const size_t pbase_out = (size_t)pp * 2 * NALL + (size_t)tbase * 16 + col;

        #pragma unroll
        for (int tt = 0; tt < TT; ++tt) {
            // ---- layer 1: C1[h-packed row, a]; rows 4g+r in lane
            f32x4 c1 = b1v;
            c1 = __builtin_amdgcn_mfma_f32_16x16x32_bf16(w1a, bf0[tt], c1, 0, 0, 0);
            c1 = __builtin_amdgcn_mfma_f32_16x16x32_bf16(w1b, bf1[tt], c1, 0, 0, 0);

            f32x4 c2;
#if __has_builtin(__builtin_amdgcn_mfma_f32_16x16x16bf16_1k)
            // ---- layer 2: C1 output layout == 16x16x16 B-fragment layout
            union { unsigned u[2]; bf16x4 v; } pb;
            pb.u[0] = pack2bf(fmaxf(c1[0], 0.f), fmaxf(c1[1], 0.f));
            pb.u[1] = pack2bf(fmaxf(c1[2], 0.f), fmaxf(c1[3], 0.f));
            c2 = __builtin_amdgcn_mfma_f32_16x16x16bf16_1k(w2v, pb.v, b2v, 0, 0, 0);
#else
            // ---- fallback: redistribute rows 4g+r -> k=8g+j via shfl, x32 MFMA
            float rl[4];
            #pragma unroll
            for (int r = 0; r < 4; ++r) rl[r] = fmaxf(c1[r], 0.f);
            bf16x8 pb8;
            #pragma unroll
            for (int j = 0; j < 8; ++j) {
                const int src = ((2 * g + (j >> 2)) << 4) + col;
                pb8[j] = (short)f2bf(__shfl(rl[j & 3], src, 64));
            }
            bf16x8 w28;
            #pragma unroll
            for (int r = 0; r < 4; ++r) { w28[r] = w2v[r]; w28[r + 4] = 0; }
            c2 = __builtin_amdgcn_mfma_f32_16x16x32_bf16(w28, pb8, b2v, 0, 0, 0);
#endif
            // ---- layer 3: 4-row partial dot + partner combine (xor 16)
            float s;
            s = fmaf(fmaxf(c2[0], 0.f), w3v[0], 0.f);
            s = fmaf(fmaxf(c2[1], 0.f), w3v[1], s);
            s = fmaf(fmaxf(c2[2], 0.f), w3v[2], s);
            s = fmaf(fmaxf(c2[3], 0.f), w3v[3], s);
            const float t = s + __shfl_xor(s, 16, 64);
            if (!(g & 1) && (tbase + tt) < NTILE) {
                const int pl = lane >> 5;               // 0: p even, 1: p odd
                out[pbase_out + (size_t)pl * NALL + tt * 16] =
                    t + (pl ? b3v.y : b3v.x);
            }
        }
    }
}

extern "C" void kernel_launch(void* const* d_in, const int* in_sizes, int n_in,
                              void* d_out, int out_size, void* d_ws, size_t ws_size,
                              hipStream_t stream) {
    const float* prop = (const float*)d_in[0];   // (128, 32)
    const float* allf = (const float*)d_in[1];   // (100000, 35)
    const float* W    = (const float*)d_in[2];   // (32, 369)
    const float* b    = (const float*)d_in[3];   // (369,)
    float* out = (float*)d_out;                  // (128, 100000, 1)
    char*  ws  = (char*)d_ws;

    prep_kernel<<<NPAIR, 256, 0, stream>>>(prop, W, b, ws);

    // 782 tile-groups (TT=8) packed 4 waves/block x 8 pair-eighths
    dim3 grid(196, NPAIR / PP);
    mlp_kernel<<<grid, 256, 0, stream>>>(allf, ws, out);
}